// Round 14
// baseline (261.304 us; speedup 1.0000x reference)
//
#include <hip/hip_runtime.h>
#include <stdint.h>

// Problem constants: B=4, T=512, S=256, V=50257.
#define DIM_B 4
#define DIM_T 512
#define DIM_S 256
#define DIM_V 50257
#define NROW   2048
#define NCHUNK 25731584u     // NROW*DIM_V/4 (exact)
#define NZBLK  100514u       // NCHUNK/256 (exact) -> no bounds check
#define NBMW   804112u       // NCHUNK/32 (exact)  -> bitmap words
#define HSZ    512           // per-row hash slots (load factor 0.5)
#define HMSK   (HSZ - 1)

// Exact magic division by 50257 for e < 2^27 (max e = 102,926,335).
// m = 175022247 = ceil(2^43/50257); verified correct in R4 (passed, absmax 0).
__device__ __forceinline__ uint32_t div50257(uint32_t e) {
    return (uint32_t)(((uint64_t)e * 175022247ULL) >> 43);
}

// ws layout: gk 4MB | gv 4MB | gbm 3.07MB  (R8 proved ws_size >= 23MB)
#define WS_GK_OFF  0ull
#define WS_GV_OFF  (4ull * NROW * HSZ)
#define WS_BM_OFF  (8ull * NROW * HSZ)

// ---- K1: per-row LDS hash build -> dump to ws + set bitmap bits ----
__global__ __launch_bounds__(256) void build_kernel(
    const float* __restrict__ p_pos,   // [B,T,S]
    const int*   __restrict__ src,     // [B,S] (int64 narrowed)
    int*         __restrict__ gk,      // [NROW*HSZ]
    float*       __restrict__ gv,      // [NROW*HSZ]
    unsigned*    __restrict__ gbm)     // [NBMW]
{
    __shared__ int   hk[HSZ];
    __shared__ float hv[HSZ];

    const int row = blockIdx.x;        // row = b*T + t
    const int b   = row >> 9;          // T = 512
    const int tid = threadIdx.x;

    for (int i = tid; i < HSZ; i += 256) { hk[i] = -1; hv[i] = 0.0f; }
    __syncthreads();

    // insert (v, p); duplicates accumulate exactly via LDS atomics
    {
        const int   v = src[b * DIM_S + tid];
        const float p = p_pos[(size_t)row * DIM_S + tid];
        int h = v & HMSK;
        while (true) {
            const int prev = atomicCAS(&hk[h], -1, v);
            if (prev == -1 || prev == v) { atomicAdd(&hv[h], p); break; }
            h = (h + 1) & HMSK;
        }
        const uint32_t chunk = ((uint32_t)row * DIM_V + (uint32_t)v) >> 2;
        atomicOr(&gbm[chunk >> 5], 1u << (chunk & 31));   // dup bits benign
    }
    __syncthreads();

    // coalesced dump (fully overwrites this row's slots every call)
    for (int i = tid; i < HSZ; i += 256) {
        gk[row * HSZ + i] = hk[i];
        gv[row * HSZ + i] = hv[i];
    }
}

// ---- K2: fused zero+patch in the PROVEN giant-grid geometry ----
// One chunk per short-lived thread: bitmap-word load (one 8B segment per
// wave, L2-resident), optional compose (1.8% of chunks, hash in L2), ONE
// float4 store, endpgm. No loop -> no loop-carried vmcnt serialization
// (R4's killer); wave churn keeps the store stream at fill rate (R12:
// 7.2 TB/s for the store-only version of this exact geometry).
__global__ __launch_bounds__(256) void fused_kernel(
    const int*      __restrict__ gk,
    const float*    __restrict__ gv,
    const unsigned* __restrict__ gbm,
    float4*         __restrict__ out4)
{
    const uint32_t g = blockIdx.x * 256u + threadIdx.x;
    const unsigned w = gbm[g >> 5];
    float4 o = make_float4(0.0f, 0.0f, 0.0f, 0.0f);
    if ((w >> (g & 31)) & 1u) {            // rare path: compose 4 lanes
        float* po = (float*)&o;
        const uint32_t e0 = g << 2;
        #pragma unroll
        for (int j = 0; j < 4; ++j) {
            const uint32_t e   = e0 + (uint32_t)j;
            const uint32_t r   = div50257(e);          // per-elem row (chunks
            const int      col = (int)(e - r * (uint32_t)DIM_V);  // may straddle)
            int   h   = col & HMSK;
            float val = 0.0f;
            while (true) {
                const int k = gk[r * HSZ + h];
                if (k == col) { val = gv[r * HSZ + h]; break; }
                if (k == -1)  break;
                h = (h + 1) & HMSK;
            }
            po[j] = val;
        }
    }
    out4[g] = o;
}

extern "C" void kernel_launch(void* const* d_in, const int* in_sizes, int n_in,
                              void* d_out, int out_size, void* d_ws, size_t ws_size,
                              hipStream_t stream) {
    const float* p_pos = (const float*)d_in[0];   // [B,T,S]
    // d_in[1] = p_target_vocab — dead data (shape-only in the reference).
    const int*   src   = (const int*)d_in[2];     // [B,S]
    float*       out   = (float*)d_out;           // [B,T,V]

    char* base = (char*)d_ws;
    int*      gk  = (int*)(base + WS_GK_OFF);
    float*    gv  = (float*)(base + WS_GV_OFF);
    unsigned* gbm = (unsigned*)(base + WS_BM_OFF);

    // K0: zero the bitmap (graph memset node, ~3.1 MB)
    hipMemsetAsync(gbm, 0, (size_t)NBMW * 4, stream);
    // K1: hash build + bitmap
    build_kernel<<<NROW, DIM_S, 0, stream>>>(p_pos, src, gk, gv, gbm);
    // K2: single-touch fused stream (giant grid, one store per thread)
    fused_kernel<<<NZBLK, 256, 0, stream>>>(gk, gv, gbm, (float4*)out);
}

// Round 15
// 143.351 us; speedup vs baseline: 1.8228x; 1.8228x over previous
//
#include <hip/hip_runtime.h>
#include <stdint.h>

// Problem constants: B=4, T=512, S=256, V=50257.
#define DIM_B 4
#define DIM_T 512
#define DIM_S 256
#define DIM_V 50257
#define NROW   2048
#define NCHUNK 25731584u     // NROW*DIM_V/4 (exact)
#define NZBLK  100514u       // NCHUNK/256 (exact) -> no bounds check
#define NWAVE  402056u       // NCHUNK/64: one 64-chunk region per wave
#define DEPTH  6             // slots per region (lambda=1.3 -> P(>6) ~ 3e-4)

// ws layout (bytes). R8 proved ws_size >= 23.07 MB; we need 21.44 MB.
#define OFF_OVFCNT 0ull
#define OFF_CNT    256ull
#define OFF_KEYS   1608704ull                 // 256 + NWAVE*4 (1608224) -> 256-aligned
#define OFF_VALS   11258112ull                // KEYS + NWAVE*6*4 (9649344) -> aligned
#define OFF_OVFK   20907520ull                // VALS + 9649344 -> aligned
#define OFF_OVFV   21169664ull                // OVFK + 64K*4
#define WS_NEEDED  (OFF_OVFV + 262144ull)     // ~21.43 MB

// ---- K1: route each raw (e, p) entry to its wave-region slot array ----
// No dedupe (duplicates are additive entries). Overflow (>DEPTH) -> list.
__global__ __launch_bounds__(256) void route_kernel(
    const float* __restrict__ p_pos,   // [B,T,S]
    const int*   __restrict__ src,     // [B,S] (int64 narrowed)
    int*       __restrict__ cnt,       // [NWAVE]
    uint32_t*  __restrict__ keys,      // [NWAVE*DEPTH]
    float*     __restrict__ vals,      // [NWAVE*DEPTH]
    int*       __restrict__ ovfcnt,
    uint32_t*  __restrict__ ovfk,
    float*     __restrict__ ovfv)
{
    const int row = blockIdx.x;            // row = b*T + t
    const int b   = row >> 9;              // T = 512
    const int tid = threadIdx.x;

    const int      v = src[b * DIM_S + tid];
    const float    p = p_pos[(size_t)row * DIM_S + tid];
    const uint32_t e = (uint32_t)row * DIM_V + (uint32_t)v;   // < 2^27
    const uint32_t w = e >> 8;                                // wave region

    const int j = atomicAdd(&cnt[w], 1);
    if (j < DEPTH) {
        keys[w * DEPTH + j] = e;
        vals[w * DEPTH + j] = p;
    } else {
        const int oj = atomicAdd(ovfcnt, 1);
        ovfk[oj] = e;
        ovfv[oj] = p;
    }
}

// ---- K2: giant-grid single-touch stream, store-FIRST ----
// One chunk per short-lived thread. The unconditional zero store is issued
// before any load (compiler-fenced), so the store issue stream is identical
// to the proven 7.2 TB/s zero_clone. Patch metadata is then read per WAVE:
// one broadcast cnt load; if nonzero, <=6 broadcast key/val loads, flat
// compares (NO hash probes, NO divergent loops - R14's killer). Owning lanes
// (~1.3/wave) overwrite their chunk with a second store: same lane + same
// address => ordered after the zero store; line is L2-resident (just written).
__global__ __launch_bounds__(256) void stream_kernel(
    const int*      __restrict__ cnt,
    const uint32_t* __restrict__ keys,
    const float*    __restrict__ vals,
    float4*         __restrict__ out4)
{
    const uint32_t g = blockIdx.x * 256u + threadIdx.x;   // chunk index

    out4[g] = make_float4(0.0f, 0.0f, 0.0f, 0.0f);        // issue store FIRST
    asm volatile("" ::: "memory");                        // keep load below store

    const uint32_t w = g >> 6;                            // wave-uniform region
    int c = cnt[w];                                       // broadcast 4B load
    if (c == 0) return;                                   // 27% of waves
    c = (c < DEPTH) ? c : DEPTH;

    float4 o = make_float4(0.0f, 0.0f, 0.0f, 0.0f);
    bool hit = false;
    #pragma unroll
    for (int i = 0; i < DEPTH; ++i) {
        if (i < c) {
            const uint32_t e = keys[w * DEPTH + i];       // broadcast
            if ((e >> 2) == g) {                          // my chunk?
                const float    pv = vals[w * DEPTH + i];  // broadcast
                const uint32_t l  = e & 3u;
                o.x += (l == 0u) ? pv : 0.0f;
                o.y += (l == 1u) ? pv : 0.0f;
                o.z += (l == 2u) ? pv : 0.0f;
                o.w += (l == 3u) ? pv : 0.0f;
                hit = true;
            }
        }
    }
    if (hit) out4[g] = o;   // second store overwrites own zero (ordered)
}

// ---- K3: drain overflow entries (runs after K2; lines L2-warm) ----
__global__ __launch_bounds__(256) void overflow_kernel(
    const int* __restrict__ ovfcnt, const uint32_t* __restrict__ ovfk,
    const float* __restrict__ ovfv, float* __restrict__ out)
{
    const int n = *ovfcnt;
    for (int i = threadIdx.x; i < n; i += 256)
        atomicAdd(out + ovfk[i], ovfv[i]);
}

// ---- Fallback: R7 proven one-pass (88.7 us) if ws is too small ----
#define HSZ  512
#define HMSK (HSZ - 1)
#define RDEPTH 4
__global__ __launch_bounds__(256) void onepass_kernel(
    const float* __restrict__ p_pos, const int* __restrict__ src,
    float* __restrict__ out)
{
    __shared__ uint32_t bkey[256][RDEPTH];
    __shared__ float    bval[256][RDEPTH];
    __shared__ int      bcnt[256];
    __shared__ uint32_t okey[DIM_S];
    __shared__ float    oval[DIM_S];
    __shared__ int      ocnt;

    const int row = blockIdx.x;
    const int b   = row >> 9;
    const int tid = threadIdx.x;

    bcnt[tid] = 0;
    if (tid == 0) ocnt = 0;
    __syncthreads();

    const long long rb   = (long long)row * DIM_V;
    const int head  = (int)((4 - (row & 3)) & 3);
    const int nvec  = (DIM_V - head) >> 2;
    const int ntail = DIM_V - head - (nvec << 2);

    {
        const int   v = src[b * DIM_S + tid];
        const float p = p_pos[(size_t)row * DIM_S + tid];
        const int   d = v - head;
        bool to_ovf = true;
        if (d >= 0 && d < (nvec << 2)) {
            const int c = d >> 2;
            const int t = c & 255;
            const int j = atomicAdd(&bcnt[t], 1);
            if (j < RDEPTH) { bkey[t][j] = (uint32_t)d; bval[t][j] = p; to_ovf = false; }
        }
        if (to_ovf) { const int j = atomicAdd(&ocnt, 1); okey[j] = (uint32_t)v; oval[j] = p; }
    }
    __syncthreads();

    uint32_t k0 = 0xFFFFFFFFu, k1 = 0xFFFFFFFFu, k2 = 0xFFFFFFFFu, k3 = 0xFFFFFFFFu;
    float    v0 = 0.f, v1 = 0.f, v2 = 0.f, v3 = 0.f;
    {
        const int c = bcnt[tid];
        if (c > 0) { k0 = bkey[tid][0]; v0 = bval[tid][0]; }
        if (c > 1) { k1 = bkey[tid][1]; v1 = bval[tid][1]; }
        if (c > 2) { k2 = bkey[tid][2]; v2 = bval[tid][2]; }
        if (c > 3) { k3 = bkey[tid][3]; v3 = bval[tid][3]; }
    }

    float* __restrict__ rowp = out + rb;
    if (tid < head)  rowp[tid] = 0.0f;
    if (tid < ntail) rowp[head + (nvec << 2) + tid] = 0.0f;

    float4* __restrict__ vp = (float4*)(rowp + head);
    #pragma unroll 2
    for (int cc = tid; cc < nvec; cc += 256) {
        const uint32_t d0 = (uint32_t)(cc << 2);
        float4 o;
        o.x = ((k0==d0    )?v0:0.f) + ((k1==d0    )?v1:0.f) + ((k2==d0    )?v2:0.f) + ((k3==d0    )?v3:0.f);
        o.y = ((k0==d0+1u)?v0:0.f) + ((k1==d0+1u)?v1:0.f) + ((k2==d0+1u)?v2:0.f) + ((k3==d0+1u)?v3:0.f);
        o.z = ((k0==d0+2u)?v0:0.f) + ((k1==d0+2u)?v1:0.f) + ((k2==d0+2u)?v2:0.f) + ((k3==d0+2u)?v3:0.f);
        o.w = ((k0==d0+3u)?v0:0.f) + ((k1==d0+3u)?v1:0.f) + ((k2==d0+3u)?v2:0.f) + ((k3==d0+3u)?v3:0.f);
        vp[cc] = o;
    }

    __syncthreads();
    for (int i = tid; i < ocnt; i += 256)
        atomicAdd(rowp + okey[i], oval[i]);
}

extern "C" void kernel_launch(void* const* d_in, const int* in_sizes, int n_in,
                              void* d_out, int out_size, void* d_ws, size_t ws_size,
                              hipStream_t stream) {
    const float* p_pos = (const float*)d_in[0];   // [B,T,S]
    // d_in[1] = p_target_vocab — dead data (shape-only in the reference).
    const int*   src   = (const int*)d_in[2];     // [B,S]
    float*       out   = (float*)d_out;           // [B,T,V]

    if (ws_size >= WS_NEEDED) {
        char* base = (char*)d_ws;
        int*      ovfcnt = (int*)(base + OFF_OVFCNT);
        int*      cnt    = (int*)(base + OFF_CNT);
        uint32_t* keys   = (uint32_t*)(base + OFF_KEYS);
        float*    vals   = (float*)(base + OFF_VALS);
        uint32_t* ovfk   = (uint32_t*)(base + OFF_OVFK);
        float*    ovfv   = (float*)(base + OFF_OVFV);

        // K0: zero ovfcnt + cnt[] (single memset node, ~1.6 MB)
        hipMemsetAsync(d_ws, 0, OFF_CNT + (size_t)NWAVE * 4, stream);
        // K1: route entries to wave-region slots
        route_kernel<<<NROW, DIM_S, 0, stream>>>(p_pos, src, cnt, keys, vals,
                                                 ovfcnt, ovfk, ovfv);
        // K2: store-first giant-grid single-touch stream
        stream_kernel<<<NZBLK, 256, 0, stream>>>(cnt, keys, vals, (float4*)out);
        // K3: overflow drain
        overflow_kernel<<<1, 256, 0, stream>>>(ovfcnt, ovfk, ovfv, out);
    } else {
        onepass_kernel<<<NROW, DIM_S, 0, stream>>>(p_pos, src, out);
    }
}